// Round 9
// baseline (7059.727 us; speedup 1.0000x reference)
//
#include <hip/hip_runtime.h>
#include <stdint.h>

typedef unsigned short u16;
typedef unsigned long long u64;
typedef __attribute__((ext_vector_type(8))) short short8;
typedef __attribute__((ext_vector_type(4))) float floatx4;

#define K_IN    4096   // INPUT_SIZE
#define HID     1024   // HIDDEN
#define G4H     4096   // 4*HIDDEN
#define T_STEPS 2048   // WINDOW
#define NWG     128    // scan workgroups; each owns 8 hidden units
#define SPIN_MAX 60000 // watchdog sweeps; then thread runs free (wrong > hung)

__device__ __forceinline__ u16 f2bf(float f) {
  union { float f; unsigned int i; } v; v.f = f;
  unsigned int lsb = (v.i >> 16) & 1u;
  v.i += 0x7fffu + lsb;
  return (u16)(v.i >> 16);
}
// NaN/Inf -> 0 via INTEGER exponent test: immune to fast-math folding.
__device__ __forceinline__ float finz(float x) {
  unsigned b = __float_as_uint(x);
  return ((b & 0x7f800000u) == 0x7f800000u) ? 0.f : x;
}
__device__ __forceinline__ float sigm(float x) {
  x = fminf(30.f, fmaxf(-30.f, finz(x)));
  return 1.0f / (1.0f + __expf(-x));
}
__device__ __forceinline__ float tanh_s(float x) {
  x = fminf(15.f, fmaxf(-15.f, finz(x)));
  float e = __expf(2.0f * x);
  return (e - 1.0f) / (e + 1.0f);
}

// tagged publish via RMW: executes AT the coherence point (no store-buffer lag).
__device__ __forceinline__ void publish_h(u64* hx, int slot, int idx, float h) {
  h = finz(h);
  u64 v = ((u64)(unsigned)(slot + 1) << 32) | (u64)__float_as_uint(h);
  (void)__hip_atomic_exchange(&hx[(size_t)slot * HID + idx], v,
                              __ATOMIC_RELAXED, __HIP_MEMORY_SCOPE_AGENT);
}

// poll 2 consecutive entries of slot for tag (slot+1); watchdog -> dead thread
__device__ __forceinline__ void poll2(const u64* hx, int slot, int j0,
                                      float* v, int* alive) {
  const u64* p = hx + (size_t)slot * HID + j0;
  const unsigned tag = (unsigned)(slot + 1);
  if (*alive) {
    int spins = 0;
    for (;;) {
      u64 a = __hip_atomic_load(&p[0], __ATOMIC_RELAXED, __HIP_MEMORY_SCOPE_AGENT);
      u64 b = __hip_atomic_load(&p[1], __ATOMIC_RELAXED, __HIP_MEMORY_SCOPE_AGENT);
      if ((unsigned)(a >> 32) == tag && (unsigned)(b >> 32) == tag) {
        v[0] = finz(__uint_as_float((unsigned)a));
        v[1] = finz(__uint_as_float((unsigned)b));
        return;
      }
      if (++spins > SPIN_MAX) { *alive = 0; break; }
      __builtin_amdgcn_s_sleep(1);
    }
  }
  v[0] = v[1] = 0.f;
}

// ---------------------------------------------------------------------------
// Phase 0: f32 -> bf16 conversion
// ---------------------------------------------------------------------------
__global__ __launch_bounds__(256) void cvt_bf16_k(const float* __restrict__ src,
                                                  u16* __restrict__ dst, int n4) {
  int i = blockIdx.x * 256 + threadIdx.x;
  if (i < n4) {
    float4 v = *(const float4*)(src + (size_t)i * 4);
    u16 o0 = f2bf(v.x), o1 = f2bf(v.y), o2 = f2bf(v.z), o3 = f2bf(v.w);
    ushort4 o = {o0, o1, o2, o3};
    *(ushort4*)(dst + (size_t)i * 4) = o;
  }
}

// ---------------------------------------------------------------------------
// Phase 1: xg = inp @ W_ih^T + b_ih (f32 out). 128x128 tile, BK=64, bf16 MFMA.
// ---------------------------------------------------------------------------
__global__ __launch_bounds__(256) void xg_gemm_k(const u16* __restrict__ A,      // [2048,4096] bf16
                                                 const u16* __restrict__ B,      // [4096,4096] bf16
                                                 const float* __restrict__ bias, // [4096] f32
                                                 float* __restrict__ C)          // [2048,4096] f32
{
  __shared__ __align__(16) u16 As[128 * 64];
  __shared__ __align__(16) u16 Bs[128 * 64];
  const int tid  = threadIdx.x;
  const int lane = tid & 63;
  const int quad = lane >> 4;
  const int l16  = lane & 15;
  const int wid  = tid >> 6;
  const int wm   = wid >> 1, wn = wid & 1;
  const int tileM = blockIdx.y * 128;
  const int tileN = blockIdx.x * 128;

  floatx4 acc[4][4];
  #pragma unroll
  for (int mi = 0; mi < 4; ++mi)
    #pragma unroll
    for (int ni = 0; ni < 4; ++ni)
      acc[mi][ni] = (floatx4){0.f, 0.f, 0.f, 0.f};

  for (int k0 = 0; k0 < K_IN; k0 += 64) {
    #pragma unroll
    for (int i = 0; i < 4; ++i) {
      int c = i * 256 + tid;
      int row = c >> 3, col = (c & 7) * 8;
      *(short8*)(As + c * 8) = *(const short8*)(A + (size_t)(tileM + row) * K_IN + k0 + col);
      *(short8*)(Bs + c * 8) = *(const short8*)(B + (size_t)(tileN + row) * K_IN + k0 + col);
    }
    __syncthreads();
    #pragma unroll
    for (int kk = 0; kk < 64; kk += 32) {
      short8 av[4], bv[4];
      #pragma unroll
      for (int mi = 0; mi < 4; ++mi)
        av[mi] = *(const short8*)(As + (wm * 64 + mi * 16 + l16) * 64 + kk + quad * 8);
      #pragma unroll
      for (int ni = 0; ni < 4; ++ni)
        bv[ni] = *(const short8*)(Bs + (wn * 64 + ni * 16 + l16) * 64 + kk + quad * 8);
      #pragma unroll
      for (int mi = 0; mi < 4; ++mi)
        #pragma unroll
        for (int ni = 0; ni < 4; ++ni)
          acc[mi][ni] = __builtin_amdgcn_mfma_f32_16x16x32_bf16(av[mi], bv[ni], acc[mi][ni], 0, 0, 0);
    }
    __syncthreads();
  }
  #pragma unroll
  for (int ni = 0; ni < 4; ++ni) {
    int n = tileN + wn * 64 + ni * 16 + l16;
    float bn = bias[n];
    #pragma unroll
    for (int mi = 0; mi < 4; ++mi) {
      int mbase = tileM + wm * 64 + mi * 16 + quad * 4;
      #pragma unroll
      for (int r = 0; r < 4; ++r)
        C[(size_t)(mbase + r) * G4H + n] = acc[mi][ni][r] + bn;
    }
  }
}

// ---------------------------------------------------------------------------
// Phase 2: persistent scan, ONE barrier per step.
// Block g owns units [8g, 8g+8). Wave w owns unit U = 8g+w — ALL 4 gates:
//   rows q*HID + U, q=0..3  (4 rows/wave, 64 FMA/lane).
// After the 64-lane butterfly, lane 0 of wave w holds i,f,g,o sums for U:
// computes c,h and publishes directly. No gsum LDS, no second barrier.
// Each thread polls/stages 2 tagged u64 entries (short detect sweep).
// ---------------------------------------------------------------------------
__global__ __launch_bounds__(512, 1) void lstm_scan_k(const float* __restrict__ Whh,
                                                      const float* __restrict__ bhh,
                                                      const float* __restrict__ h1,
                                                      const float* __restrict__ c1,
                                                      const float* __restrict__ fcw,
                                                      const float* __restrict__ fcb,
                                                      const float* __restrict__ xg,
                                                      u64* hx,        // [T_STEPS+1][1024]
                                                      float* out)     // [2080] f32
{
  const int g    = blockIdx.x;
  const int tid  = threadIdx.x;
  const int lane = tid & 63;
  const int w    = tid >> 6;           // wave 0..7
  const int U    = g * 8 + w;          // this wave's hidden unit

  __shared__ float h_local[HID];
  __shared__ float pp[32][16];         // final FC partials

  // W_hh rows q*HID+U, q=0..3 -> VGPRs (coalesced 64x4B per (q,j))
  float wreg[4][16];
  #pragma unroll
  for (int q = 0; q < 4; ++q) {
    const size_t row = (size_t)(q * HID + U);
    #pragma unroll
    for (int j = 0; j < 16; ++j)
      wreg[q][j] = Whh[row * HID + j * 64 + lane];
  }

  float bq[4] = {0.f, 0.f, 0.f, 0.f};
  float c_state = 0.f;
  if (lane == 0) {
    #pragma unroll
    for (int q = 0; q < 4; ++q) bq[q] = bhh[q * HID + U];
    c_state = c1[U];
    publish_h(hx, 0, U, h1[U]);
  }

  int alive = 1;
  const int j0 = tid * 2;              // 512 threads x 2 entries = 1024
  for (int t = 0; t < T_STEPS; ++t) {
    // lane 0 prefetches this unit's 4 xg values (overlaps the poll)
    float xq[4] = {0.f, 0.f, 0.f, 0.f};
    if (lane == 0) {
      const size_t xb = (size_t)t * G4H + U;
      #pragma unroll
      for (int q = 0; q < 4; ++q) xq[q] = finz(xg[xb + q * HID]);
    }

    float v[2];
    poll2(hx, t, j0, v, &alive);
    h_local[j0 + 0] = v[0]; h_local[j0 + 1] = v[1];
    __syncthreads();

    // 4 gate-row dots for unit U; h_local reads lane-strided (2-way alias = free)
    float s[4] = {0.f, 0.f, 0.f, 0.f};
    #pragma unroll
    for (int j = 0; j < 16; ++j) {
      float hv = h_local[j * 64 + lane];
      #pragma unroll
      for (int q = 0; q < 4; ++q) s[q] = fmaf(wreg[q][j], hv, s[q]);
    }
    #pragma unroll
    for (int d = 1; d < 64; d <<= 1) {
      #pragma unroll
      for (int q = 0; q < 4; ++q) s[q] += __shfl_xor(s[q], d, 64);
    }

    // lane 0: gates + state + publish (no second barrier, no LDS handoff)
    if (lane == 0) {
      float gi = s[0] + xq[0] + bq[0];
      float gf = s[1] + xq[1] + bq[1];
      float gg = s[2] + xq[2] + bq[2];
      float go = s[3] + xq[3] + bq[3];
      float iv = sigm(gi), fv = sigm(gf), gv = tanh_s(gg), ov = sigm(go);
      c_state = finz(fv * c_state + iv * gv);
      float hval = ov * tanh_s(c_state);
      publish_h(hx, t + 1, U, hval);
      if (t == 1023) {                 // hs[STRIDE-1], cs[STRIDE-1]
        out[32 + U]       = finz(hval);
        out[32 + HID + U] = finz(c_state);
      }
    }
  }

  // out[0:32] = tanh(h_fin @ fc_w^T + fc_b): block 0 only
  if (g == 0) {
    float v[2];
    poll2(hx, T_STEPS, j0, v, &alive);
    h_local[j0 + 0] = v[0]; h_local[j0 + 1] = v[1];
    __syncthreads();
    const int m = tid >> 4, seg = tid & 15;   // 32 rows x 16 partials of 64
    float pacc = 0.f;
    for (int k = seg * 64; k < seg * 64 + 64; ++k)
      pacc = fmaf(fcw[m * HID + k], h_local[k], pacc);
    pp[m][seg] = finz(pacc);
    __syncthreads();
    if (tid < 32) {
      float sum = fcb[tid];
      #pragma unroll
      for (int i = 0; i < 16; ++i) sum += pp[tid][i];
      out[tid] = tanh_s(finz(sum));
    }
  }
}

extern "C" void kernel_launch(void* const* d_in, const int* in_sizes, int n_in,
                              void* d_out, int out_size, void* d_ws, size_t ws_size,
                              hipStream_t stream) {
  const float* inp = (const float*)d_in[0];
  const float* h1  = (const float*)d_in[1];
  const float* c1  = (const float*)d_in[2];
  const float* Wih = (const float*)d_in[3];
  const float* Whh = (const float*)d_in[4];
  const float* bih = (const float*)d_in[5];
  const float* bhh = (const float*)d_in[6];
  const float* fcw = (const float*)d_in[7];
  const float* fcb = (const float*)d_in[8];
  float* out = (float*)d_out;

  const size_t xg_bytes  = (size_t)T_STEPS * G4H * 4;             // 33.5 MB
  const size_t hx_bytes  = (size_t)(T_STEPS + 1) * HID * 8;       // 16.8 MB
  const size_t ab_bytes  = (size_t)T_STEPS * K_IN * 2;            // 16.8 MB
  const size_t wb_bytes  = (size_t)G4H * K_IN * 2;                // 33.5 MB
  if (ws_size < xg_bytes + hx_bytes + ab_bytes + wb_bytes) return;

  float* xg   = (float*)d_ws;
  u64*   hx   = (u64*)((char*)d_ws + xg_bytes);
  u16*   Abf  = (u16*)((char*)d_ws + xg_bytes + hx_bytes);
  u16*   Wbf  = (u16*)((char*)d_ws + xg_bytes + hx_bytes + ab_bytes);

  const int nA4 = T_STEPS * K_IN / 4;
  const int nW4 = G4H * K_IN / 4;
  cvt_bf16_k<<<dim3((nA4 + 255) / 256), 256, 0, stream>>>(inp, Abf, nA4);
  cvt_bf16_k<<<dim3((nW4 + 255) / 256), 256, 0, stream>>>(Wih, Wbf, nW4);
  xg_gemm_k<<<dim3(G4H / 128, T_STEPS / 128), 256, 0, stream>>>(Abf, Wbf, bih, xg);
  lstm_scan_k<<<dim3(NWG), 512, 0, stream>>>(Whh, bhh, h1, c1, fcw, fcb, xg, hx, out);
}

// Round 10
// 6873.518 us; speedup vs baseline: 1.0271x; 1.0271x over previous
//
#include <hip/hip_runtime.h>
#include <stdint.h>

typedef unsigned short u16;
typedef unsigned int u32;
typedef unsigned long long u64;
typedef __attribute__((ext_vector_type(8))) short short8;
typedef __attribute__((ext_vector_type(4))) float floatx4;

#define K_IN    4096   // INPUT_SIZE
#define HID     1024   // HIDDEN
#define NENT    512    // packed entries per slot (2 units / entry)
#define G4H     4096   // 4*HIDDEN
#define T_STEPS 2048   // WINDOW
#define NWG     128    // scan workgroups; each owns 8 hidden units
#define SPIN_MAX 60000 // watchdog sweeps; then thread runs free (wrong > hung)

__device__ __forceinline__ u16 f2bf(float f) {
  union { float f; unsigned int i; } v; v.f = f;
  unsigned int lsb = (v.i >> 16) & 1u;
  v.i += 0x7fffu + lsb;
  return (u16)(v.i >> 16);
}
// NaN/Inf -> 0 via INTEGER exponent test: immune to fast-math folding.
__device__ __forceinline__ float finz(float x) {
  unsigned b = __float_as_uint(x);
  return ((b & 0x7f800000u) == 0x7f800000u) ? 0.f : x;
}
__device__ __forceinline__ u16 f2h_bits(float f) {
  union { _Float16 h; u16 u; } c; c.h = (_Float16)f; return c.u;
}
__device__ __forceinline__ float h2f(u16 b) {
  union { u16 u; _Float16 h; } c; c.u = b; return (float)c.h;
}
__device__ __forceinline__ float sigm(float x) {
  x = fminf(30.f, fmaxf(-30.f, finz(x)));
  return 1.0f / (1.0f + __expf(-x));
}
__device__ __forceinline__ float tanh_s(float x) {
  x = fminf(15.f, fmaxf(-15.f, finz(x)));
  float e = __expf(2.0f * x);
  return (e - 1.0f) / (e + 1.0f);
}

// packed tagged publish (PLAIN relaxed store — R9 showed RMW is 4x write traffic
// and slower): entry = (slot+1)<<32 | f16(h_odd)<<16 | f16(h_even).
__device__ __forceinline__ void publish_pair(u64* hx, int slot, int e, u32 payload) {
  u64 v = ((u64)(unsigned)(slot + 1) << 32) | (u64)payload;
  __hip_atomic_store(&hx[(size_t)slot * NENT + e], v,
                     __ATOMIC_RELAXED, __HIP_MEMORY_SCOPE_AGENT);
}

// poll ONE packed entry of slot for tag (slot+1); watchdog -> dead thread
__device__ __forceinline__ void poll1(const u64* hx, int slot, int e,
                                      float* lo, float* hi, int* alive) {
  const u64* p = hx + (size_t)slot * NENT + e;
  const unsigned tag = (unsigned)(slot + 1);
  if (*alive) {
    int spins = 0;
    for (;;) {
      u64 a = __hip_atomic_load(p, __ATOMIC_RELAXED, __HIP_MEMORY_SCOPE_AGENT);
      if ((unsigned)(a >> 32) == tag) {
        *lo = finz(h2f((u16)(a & 0xffffu)));
        *hi = finz(h2f((u16)((a >> 16) & 0xffffu)));
        return;
      }
      if (++spins > SPIN_MAX) { *alive = 0; break; }
      __builtin_amdgcn_s_sleep(1);
    }
  }
  *lo = *hi = 0.f;
}

// ---------------------------------------------------------------------------
// Phase 0: f32 -> bf16 conversion
// ---------------------------------------------------------------------------
__global__ __launch_bounds__(256) void cvt_bf16_k(const float* __restrict__ src,
                                                  u16* __restrict__ dst, int n4) {
  int i = blockIdx.x * 256 + threadIdx.x;
  if (i < n4) {
    float4 v = *(const float4*)(src + (size_t)i * 4);
    u16 o0 = f2bf(v.x), o1 = f2bf(v.y), o2 = f2bf(v.z), o3 = f2bf(v.w);
    ushort4 o = {o0, o1, o2, o3};
    *(ushort4*)(dst + (size_t)i * 4) = o;
  }
}

// ---------------------------------------------------------------------------
// Phase 1: xg = inp @ W_ih^T + b_ih (f32 out). 128x128 tile, BK=64, bf16 MFMA.
// ---------------------------------------------------------------------------
__global__ __launch_bounds__(256) void xg_gemm_k(const u16* __restrict__ A,      // [2048,4096] bf16
                                                 const u16* __restrict__ B,      // [4096,4096] bf16
                                                 const float* __restrict__ bias, // [4096] f32
                                                 float* __restrict__ C)          // [2048,4096] f32
{
  __shared__ __align__(16) u16 As[128 * 64];
  __shared__ __align__(16) u16 Bs[128 * 64];
  const int tid  = threadIdx.x;
  const int lane = tid & 63;
  const int quad = lane >> 4;
  const int l16  = lane & 15;
  const int wid  = tid >> 6;
  const int wm   = wid >> 1, wn = wid & 1;
  const int tileM = blockIdx.y * 128;
  const int tileN = blockIdx.x * 128;

  floatx4 acc[4][4];
  #pragma unroll
  for (int mi = 0; mi < 4; ++mi)
    #pragma unroll
    for (int ni = 0; ni < 4; ++ni)
      acc[mi][ni] = (floatx4){0.f, 0.f, 0.f, 0.f};

  for (int k0 = 0; k0 < K_IN; k0 += 64) {
    #pragma unroll
    for (int i = 0; i < 4; ++i) {
      int c = i * 256 + tid;
      int row = c >> 3, col = (c & 7) * 8;
      *(short8*)(As + c * 8) = *(const short8*)(A + (size_t)(tileM + row) * K_IN + k0 + col);
      *(short8*)(Bs + c * 8) = *(const short8*)(B + (size_t)(tileN + row) * K_IN + k0 + col);
    }
    __syncthreads();
    #pragma unroll
    for (int kk = 0; kk < 64; kk += 32) {
      short8 av[4], bv[4];
      #pragma unroll
      for (int mi = 0; mi < 4; ++mi)
        av[mi] = *(const short8*)(As + (wm * 64 + mi * 16 + l16) * 64 + kk + quad * 8);
      #pragma unroll
      for (int ni = 0; ni < 4; ++ni)
        bv[ni] = *(const short8*)(Bs + (wn * 64 + ni * 16 + l16) * 64 + kk + quad * 8);
      #pragma unroll
      for (int mi = 0; mi < 4; ++mi)
        #pragma unroll
        for (int ni = 0; ni < 4; ++ni)
          acc[mi][ni] = __builtin_amdgcn_mfma_f32_16x16x32_bf16(av[mi], bv[ni], acc[mi][ni], 0, 0, 0);
    }
    __syncthreads();
  }
  #pragma unroll
  for (int ni = 0; ni < 4; ++ni) {
    int n = tileN + wn * 64 + ni * 16 + l16;
    float bn = bias[n];
    #pragma unroll
    for (int mi = 0; mi < 4; ++mi) {
      int mbase = tileM + wm * 64 + mi * 16 + quad * 4;
      #pragma unroll
      for (int r = 0; r < 4; ++r)
        C[(size_t)(mbase + r) * G4H + n] = acc[mi][ni][r] + bn;
    }
  }
}

// ---------------------------------------------------------------------------
// Phase 2: persistent scan, ONE barrier per step, PACKED f16-pair exchange.
// Block g owns units [8g, 8g+8). Wave w owns unit U = 8g+w (all 4 gate rows).
// After butterfly+gates, odd wave's lane0 drops (tag16|f16) into a 4B LDS word;
// even wave's lane0 spins locally, packs the pair, publishes ONE u64 entry.
// Consumers: thread tid polls exactly ONE packed entry (minimum sweep).
// ---------------------------------------------------------------------------
__global__ __launch_bounds__(512, 1) void lstm_scan_k(const float* __restrict__ Whh,
                                                      const float* __restrict__ bhh,
                                                      const float* __restrict__ h1,
                                                      const float* __restrict__ c1,
                                                      const float* __restrict__ fcw,
                                                      const float* __restrict__ fcb,
                                                      const float* __restrict__ xg,
                                                      u64* hx,        // [T_STEPS+1][512]
                                                      float* out)     // [2080] f32
{
  const int g    = blockIdx.x;
  const int tid  = threadIdx.x;
  const int lane = tid & 63;
  const int w    = tid >> 6;           // wave 0..7
  const int U    = g * 8 + w;          // this wave's hidden unit

  __shared__ float h_local[HID];
  __shared__ u32 pair_lds[8];          // per-wave (tag16<<16)|f16bits(h)
  __shared__ float pp[32][16];         // final FC partials

  // W_hh rows q*HID+U, q=0..3 -> VGPRs
  float wreg[4][16];
  #pragma unroll
  for (int q = 0; q < 4; ++q) {
    const size_t row = (size_t)(q * HID + U);
    #pragma unroll
    for (int j = 0; j < 16; ++j)
      wreg[q][j] = Whh[row * HID + j * 64 + lane];
  }

  float bq[4] = {0.f, 0.f, 0.f, 0.f};
  float c_state = 0.f;
  if (lane == 0) {
    #pragma unroll
    for (int q = 0; q < 4; ++q) bq[q] = bhh[q * HID + U];
    c_state = c1[U];
    pair_lds[w] = 0;                   // tag16=0 never matches (t+1 >= 1)
  }
  // initial publish of slot 0 (h1), packed: wave 0 lanes 0..3
  if (w == 0 && lane < 4) {
    float lo = finz(h1[g * 8 + 2 * lane]);
    float hi = finz(h1[g * 8 + 2 * lane + 1]);
    u32 payload = ((u32)f2h_bits(hi) << 16) | (u32)f2h_bits(lo);
    publish_pair(hx, 0, g * 4 + lane, payload);
  }

  int alive = 1;
  for (int t = 0; t < T_STEPS; ++t) {
    // lane 0 prefetches this unit's 4 xg values (overlaps the poll)
    float xq[4] = {0.f, 0.f, 0.f, 0.f};
    if (lane == 0) {
      const size_t xb = (size_t)t * G4H + U;
      #pragma unroll
      for (int q = 0; q < 4; ++q) xq[q] = finz(xg[xb + q * HID]);
    }

    float lo, hi;
    poll1(hx, t, tid, &lo, &hi, &alive);     // entry tid -> units 2*tid, 2*tid+1
    h_local[2 * tid]     = lo;
    h_local[2 * tid + 1] = hi;
    __syncthreads();                          // also orders pair_lds init/reuse

    // 4 gate-row dots for unit U; h_local reads lane-strided
    float s[4] = {0.f, 0.f, 0.f, 0.f};
    #pragma unroll
    for (int j = 0; j < 16; ++j) {
      float hv = h_local[j * 64 + lane];
      #pragma unroll
      for (int q = 0; q < 4; ++q) s[q] = fmaf(wreg[q][j], hv, s[q]);
    }
    #pragma unroll
    for (int d = 1; d < 64; d <<= 1) {
      #pragma unroll
      for (int q = 0; q < 4; ++q) s[q] += __shfl_xor(s[q], d, 64);
    }

    if (lane == 0) {
      float gi = s[0] + xq[0] + bq[0];
      float gf = s[1] + xq[1] + bq[1];
      float gg = s[2] + xq[2] + bq[2];
      float go = s[3] + xq[3] + bq[3];
      float iv = sigm(gi), fv = sigm(gf), gv = tanh_s(gg), ov = sigm(go);
      c_state = finz(fv * c_state + iv * gv);
      float hval = ov * tanh_s(c_state);
      const u32 tag16 = (u32)((t + 1) & 0xffff);
      const u32 myv = (tag16 << 16) | (u32)f2h_bits(hval);
      if (w & 1) {
        // odd wave: hand my h to the even partner via a single 4B LDS word
        __hip_atomic_store(&pair_lds[w], myv, __ATOMIC_RELAXED,
                           __HIP_MEMORY_SCOPE_WORKGROUP);
      } else {
        // even wave: spin for partner (intra-CU, ~LDS latency), pack, publish
        u32 pv = 0; int spins = 0;
        for (;;) {
          pv = __hip_atomic_load(&pair_lds[w + 1], __ATOMIC_RELAXED,
                                 __HIP_MEMORY_SCOPE_WORKGROUP);
          if ((pv >> 16) == tag16) break;
          if (++spins > SPIN_MAX) { pv = 0; break; }
        }
        u32 payload = ((pv & 0xffffu) << 16) | (myv & 0xffffu);
        publish_pair(hx, t + 1, g * 4 + (w >> 1), payload);
      }
      if (t == 1023) {                 // hs[STRIDE-1], cs[STRIDE-1] (exact f32)
        out[32 + U]       = finz(hval);
        out[32 + HID + U] = finz(c_state);
      }
    }
  }

  // out[0:32] = tanh(h_fin @ fc_w^T + fc_b): block 0 only
  if (g == 0) {
    float lo, hi;
    poll1(hx, T_STEPS, tid, &lo, &hi, &alive);
    h_local[2 * tid]     = lo;
    h_local[2 * tid + 1] = hi;
    __syncthreads();
    const int m = tid >> 4, seg = tid & 15;   // 32 rows x 16 partials of 64
    float pacc = 0.f;
    for (int k = seg * 64; k < seg * 64 + 64; ++k)
      pacc = fmaf(fcw[m * HID + k], h_local[k], pacc);
    pp[m][seg] = finz(pacc);
    __syncthreads();
    if (tid < 32) {
      float sum = fcb[tid];
      #pragma unroll
      for (int i = 0; i < 16; ++i) sum += pp[tid][i];
      out[tid] = tanh_s(finz(sum));
    }
  }
}

extern "C" void kernel_launch(void* const* d_in, const int* in_sizes, int n_in,
                              void* d_out, int out_size, void* d_ws, size_t ws_size,
                              hipStream_t stream) {
  const float* inp = (const float*)d_in[0];
  const float* h1  = (const float*)d_in[1];
  const float* c1  = (const float*)d_in[2];
  const float* Wih = (const float*)d_in[3];
  const float* Whh = (const float*)d_in[4];
  const float* bih = (const float*)d_in[5];
  const float* bhh = (const float*)d_in[6];
  const float* fcw = (const float*)d_in[7];
  const float* fcb = (const float*)d_in[8];
  float* out = (float*)d_out;

  const size_t xg_bytes  = (size_t)T_STEPS * G4H * 4;             // 33.5 MB
  const size_t hx_bytes  = (size_t)(T_STEPS + 1) * NENT * 8;      // 8.4 MB
  const size_t ab_bytes  = (size_t)T_STEPS * K_IN * 2;            // 16.8 MB
  const size_t wb_bytes  = (size_t)G4H * K_IN * 2;                // 33.5 MB
  if (ws_size < xg_bytes + hx_bytes + ab_bytes + wb_bytes) return;

  float* xg   = (float*)d_ws;
  u64*   hx   = (u64*)((char*)d_ws + xg_bytes);
  u16*   Abf  = (u16*)((char*)d_ws + xg_bytes + hx_bytes);
  u16*   Wbf  = (u16*)((char*)d_ws + xg_bytes + hx_bytes + ab_bytes);

  const int nA4 = T_STEPS * K_IN / 4;
  const int nW4 = G4H * K_IN / 4;
  cvt_bf16_k<<<dim3((nA4 + 255) / 256), 256, 0, stream>>>(inp, Abf, nA4);
  cvt_bf16_k<<<dim3((nW4 + 255) / 256), 256, 0, stream>>>(Wih, Wbf, nW4);
  xg_gemm_k<<<dim3(G4H / 128, T_STEPS / 128), 256, 0, stream>>>(Abf, Wbf, bih, xg);
  lstm_scan_k<<<dim3(NWG), 512, 0, stream>>>(Whh, bhh, h1, c1, fcw, fcb, xg, hx, out);
}

// Round 11
// 6437.849 us; speedup vs baseline: 1.0966x; 1.0677x over previous
//
#include <hip/hip_runtime.h>
#include <stdint.h>

typedef unsigned short u16;
typedef unsigned int u32;
typedef unsigned long long u64;
typedef __attribute__((ext_vector_type(8))) short short8;
typedef __attribute__((ext_vector_type(4))) float floatx4;

#define K_IN    4096   // INPUT_SIZE
#define HID     1024   // HIDDEN
#define G4H     4096   // 4*HIDDEN
#define T_STEPS 2048   // WINDOW
#define NWG     128    // scan workgroups; each owns 8 hidden units
#define SPIN_MAX 200000 // watchdog (no-sleep spin ~500cyc/iter -> ~40ms); wrong > hung

__device__ __forceinline__ u16 f2bf(float f) {
  union { float f; unsigned int i; } v; v.f = f;
  unsigned int lsb = (v.i >> 16) & 1u;
  v.i += 0x7fffu + lsb;
  return (u16)(v.i >> 16);
}
// NaN/Inf -> 0 via INTEGER exponent test: immune to fast-math folding.
__device__ __forceinline__ float finz(float x) {
  unsigned b = __float_as_uint(x);
  return ((b & 0x7f800000u) == 0x7f800000u) ? 0.f : x;
}
__device__ __forceinline__ float sigm(float x) {
  x = fminf(30.f, fmaxf(-30.f, finz(x)));
  return 1.0f / (1.0f + __expf(-x));
}
__device__ __forceinline__ float tanh_s(float x) {
  x = fminf(15.f, fmaxf(-15.f, finz(x)));
  float e = __expf(2.0f * x);
  return (e - 1.0f) / (e + 1.0f);
}

// tagged publish: PLAIN relaxed atomic store (R9: RMW = 4x writes + slower).
// Block g's 8 publishes fill one 64B sector (units 8g..8g+7) — no false sharing.
__device__ __forceinline__ void publish_h(u64* hx, int slot, int idx, float h) {
  h = finz(h);
  u64 v = ((u64)(unsigned)(slot + 1) << 32) | (u64)__float_as_uint(h);
  __hip_atomic_store(&hx[(size_t)slot * HID + idx], v,
                     __ATOMIC_RELAXED, __HIP_MEMORY_SCOPE_AGENT);
}

// poll 2 consecutive entries of slot for tag (slot+1); hard spin (no sleep);
// watchdog -> dead thread (terminates wrong rather than hangs)
__device__ __forceinline__ void poll2(const u64* hx, int slot, int j0,
                                      float* v, int* alive) {
  const u64* p = hx + (size_t)slot * HID + j0;
  const unsigned tag = (unsigned)(slot + 1);
  if (*alive) {
    int spins = 0;
    for (;;) {
      u64 a = __hip_atomic_load(&p[0], __ATOMIC_RELAXED, __HIP_MEMORY_SCOPE_AGENT);
      u64 b = __hip_atomic_load(&p[1], __ATOMIC_RELAXED, __HIP_MEMORY_SCOPE_AGENT);
      if ((unsigned)(a >> 32) == tag && (unsigned)(b >> 32) == tag) {
        v[0] = finz(__uint_as_float((unsigned)a));
        v[1] = finz(__uint_as_float((unsigned)b));
        return;
      }
      if (++spins > SPIN_MAX) { *alive = 0; break; }
    }
  }
  v[0] = v[1] = 0.f;
}

// ---------------------------------------------------------------------------
// Phase 0: f32 -> bf16 conversion
// ---------------------------------------------------------------------------
__global__ __launch_bounds__(256) void cvt_bf16_k(const float* __restrict__ src,
                                                  u16* __restrict__ dst, int n4) {
  int i = blockIdx.x * 256 + threadIdx.x;
  if (i < n4) {
    float4 v = *(const float4*)(src + (size_t)i * 4);
    u16 o0 = f2bf(v.x), o1 = f2bf(v.y), o2 = f2bf(v.z), o3 = f2bf(v.w);
    ushort4 o = {o0, o1, o2, o3};
    *(ushort4*)(dst + (size_t)i * 4) = o;
  }
}

// ---------------------------------------------------------------------------
// Phase 1: xg = inp @ W_ih^T + b_ih (f32 out). 128x128 tile, BK=64, bf16 MFMA.
// ---------------------------------------------------------------------------
__global__ __launch_bounds__(256) void xg_gemm_k(const u16* __restrict__ A,      // [2048,4096] bf16
                                                 const u16* __restrict__ B,      // [4096,4096] bf16
                                                 const float* __restrict__ bias, // [4096] f32
                                                 float* __restrict__ C)          // [2048,4096] f32
{
  __shared__ __align__(16) u16 As[128 * 64];
  __shared__ __align__(16) u16 Bs[128 * 64];
  const int tid  = threadIdx.x;
  const int lane = tid & 63;
  const int quad = lane >> 4;
  const int l16  = lane & 15;
  const int wid  = tid >> 6;
  const int wm   = wid >> 1, wn = wid & 1;
  const int tileM = blockIdx.y * 128;
  const int tileN = blockIdx.x * 128;

  floatx4 acc[4][4];
  #pragma unroll
  for (int mi = 0; mi < 4; ++mi)
    #pragma unroll
    for (int ni = 0; ni < 4; ++ni)
      acc[mi][ni] = (floatx4){0.f, 0.f, 0.f, 0.f};

  for (int k0 = 0; k0 < K_IN; k0 += 64) {
    #pragma unroll
    for (int i = 0; i < 4; ++i) {
      int c = i * 256 + tid;
      int row = c >> 3, col = (c & 7) * 8;
      *(short8*)(As + c * 8) = *(const short8*)(A + (size_t)(tileM + row) * K_IN + k0 + col);
      *(short8*)(Bs + c * 8) = *(const short8*)(B + (size_t)(tileN + row) * K_IN + k0 + col);
    }
    __syncthreads();
    #pragma unroll
    for (int kk = 0; kk < 64; kk += 32) {
      short8 av[4], bv[4];
      #pragma unroll
      for (int mi = 0; mi < 4; ++mi)
        av[mi] = *(const short8*)(As + (wm * 64 + mi * 16 + l16) * 64 + kk + quad * 8);
      #pragma unroll
      for (int ni = 0; ni < 4; ++ni)
        bv[ni] = *(const short8*)(Bs + (wn * 64 + ni * 16 + l16) * 64 + kk + quad * 8);
      #pragma unroll
      for (int mi = 0; mi < 4; ++mi)
        #pragma unroll
        for (int ni = 0; ni < 4; ++ni)
          acc[mi][ni] = __builtin_amdgcn_mfma_f32_16x16x32_bf16(av[mi], bv[ni], acc[mi][ni], 0, 0, 0);
    }
    __syncthreads();
  }
  #pragma unroll
  for (int ni = 0; ni < 4; ++ni) {
    int n = tileN + wn * 64 + ni * 16 + l16;
    float bn = bias[n];
    #pragma unroll
    for (int mi = 0; mi < 4; ++mi) {
      int mbase = tileM + wm * 64 + mi * 16 + quad * 4;
      #pragma unroll
      for (int r = 0; r < 4; ++r)
        C[(size_t)(mbase + r) * G4H + n] = acc[mi][ni][r] + bn;
    }
  }
}

// ---------------------------------------------------------------------------
// Phase 2: persistent scan, ONE barrier per step (R8 poll + R9 per-wave gates,
// store-publish). Block g owns units [8g,8g+8); wave w owns unit U = 8g+w,
// all 4 gate rows (q*HID+U). After the butterfly, lane 0 computes gates/state
// and publishes directly — no gsum LDS, no second barrier.
// h_local is PARITY double-buffered: without barrier #2 a far-ahead wave could
// re-stage while a delayed sibling still reads; parity closes that race.
// ---------------------------------------------------------------------------
__global__ __launch_bounds__(512, 1) void lstm_scan_k(const float* __restrict__ Whh,
                                                      const float* __restrict__ bhh,
                                                      const float* __restrict__ h1,
                                                      const float* __restrict__ c1,
                                                      const float* __restrict__ fcw,
                                                      const float* __restrict__ fcb,
                                                      const float* __restrict__ xg,
                                                      u64* hx,        // [T_STEPS+1][1024]
                                                      float* out)     // [2080] f32
{
  const int g    = blockIdx.x;
  const int tid  = threadIdx.x;
  const int lane = tid & 63;
  const int w    = tid >> 6;           // wave 0..7
  const int U    = g * 8 + w;          // this wave's hidden unit

  __shared__ float h_local[2][HID];    // parity double-buffer
  __shared__ float pp[32][16];         // final FC partials

  // W_hh rows q*HID+U, q=0..3 -> VGPRs (coalesced 64x4B per (q,j))
  float wreg[4][16];
  #pragma unroll
  for (int q = 0; q < 4; ++q) {
    const size_t row = (size_t)(q * HID + U);
    #pragma unroll
    for (int j = 0; j < 16; ++j)
      wreg[q][j] = Whh[row * HID + j * 64 + lane];
  }

  float bq[4] = {0.f, 0.f, 0.f, 0.f};
  float c_state = 0.f;
  if (lane == 0) {
    #pragma unroll
    for (int q = 0; q < 4; ++q) bq[q] = bhh[q * HID + U];
    c_state = c1[U];
    publish_h(hx, 0, U, h1[U]);        // 8 waves fill block g's 64B sector
  }

  int alive = 1;
  const int j0 = tid * 2;              // 512 threads x 2 entries = 1024
  for (int t = 0; t < T_STEPS; ++t) {
    float* hl = h_local[t & 1];
    // lane 0 prefetches this unit's 4 xg values (overlaps the poll)
    float xq[4] = {0.f, 0.f, 0.f, 0.f};
    if (lane == 0) {
      const size_t xb = (size_t)t * G4H + U;
      #pragma unroll
      for (int q = 0; q < 4; ++q) xq[q] = finz(xg[xb + q * HID]);
    }

    float v[2];
    poll2(hx, t, j0, v, &alive);
    *(float2*)(hl + j0) = make_float2(v[0], v[1]);
    __syncthreads();

    // 4 gate-row dots for unit U; lane-strided reads (2-way alias = free)
    float s[4] = {0.f, 0.f, 0.f, 0.f};
    #pragma unroll
    for (int j = 0; j < 16; ++j) {
      float hv = hl[j * 64 + lane];
      #pragma unroll
      for (int q = 0; q < 4; ++q) s[q] = fmaf(wreg[q][j], hv, s[q]);
    }
    #pragma unroll
    for (int d = 1; d < 64; d <<= 1) {
      #pragma unroll
      for (int q = 0; q < 4; ++q) s[q] += __shfl_xor(s[q], d, 64);
    }

    // lane 0: gates + state + publish (no second barrier, no LDS handoff)
    if (lane == 0) {
      float gi = s[0] + xq[0] + bq[0];
      float gf = s[1] + xq[1] + bq[1];
      float gg = s[2] + xq[2] + bq[2];
      float go = s[3] + xq[3] + bq[3];
      float iv = sigm(gi), fv = sigm(gf), gv = tanh_s(gg), ov = sigm(go);
      c_state = finz(fv * c_state + iv * gv);
      float hval = ov * tanh_s(c_state);
      publish_h(hx, t + 1, U, hval);
      if (t == 1023) {                 // hs[STRIDE-1], cs[STRIDE-1]
        out[32 + U]       = finz(hval);
        out[32 + HID + U] = finz(c_state);
      }
    }
  }

  // out[0:32] = tanh(h_fin @ fc_w^T + fc_b): block 0 only
  if (g == 0) {
    float* hl = h_local[T_STEPS & 1];
    float v[2];
    poll2(hx, T_STEPS, j0, v, &alive);
    *(float2*)(hl + j0) = make_float2(v[0], v[1]);
    __syncthreads();
    const int m = tid >> 4, seg = tid & 15;   // 32 rows x 16 partials of 64
    float pacc = 0.f;
    for (int k = seg * 64; k < seg * 64 + 64; ++k)
      pacc = fmaf(fcw[m * HID + k], hl[k], pacc);
    pp[m][seg] = finz(pacc);
    __syncthreads();
    if (tid < 32) {
      float sum = fcb[tid];
      #pragma unroll
      for (int i = 0; i < 16; ++i) sum += pp[tid][i];
      out[tid] = tanh_s(finz(sum));
    }
  }
}

extern "C" void kernel_launch(void* const* d_in, const int* in_sizes, int n_in,
                              void* d_out, int out_size, void* d_ws, size_t ws_size,
                              hipStream_t stream) {
  const float* inp = (const float*)d_in[0];
  const float* h1  = (const float*)d_in[1];
  const float* c1  = (const float*)d_in[2];
  const float* Wih = (const float*)d_in[3];
  const float* Whh = (const float*)d_in[4];
  const float* bih = (const float*)d_in[5];
  const float* bhh = (const float*)d_in[6];
  const float* fcw = (const float*)d_in[7];
  const float* fcb = (const float*)d_in[8];
  float* out = (float*)d_out;

  const size_t xg_bytes  = (size_t)T_STEPS * G4H * 4;             // 33.5 MB
  const size_t hx_bytes  = (size_t)(T_STEPS + 1) * HID * 8;       // 16.8 MB
  const size_t ab_bytes  = (size_t)T_STEPS * K_IN * 2;            // 16.8 MB
  const size_t wb_bytes  = (size_t)G4H * K_IN * 2;                // 33.5 MB
  if (ws_size < xg_bytes + hx_bytes + ab_bytes + wb_bytes) return;

  float* xg   = (float*)d_ws;
  u64*   hx   = (u64*)((char*)d_ws + xg_bytes);
  u16*   Abf  = (u16*)((char*)d_ws + xg_bytes + hx_bytes);
  u16*   Wbf  = (u16*)((char*)d_ws + xg_bytes + hx_bytes + ab_bytes);

  const int nA4 = T_STEPS * K_IN / 4;
  const int nW4 = G4H * K_IN / 4;
  cvt_bf16_k<<<dim3((nA4 + 255) / 256), 256, 0, stream>>>(inp, Abf, nA4);
  cvt_bf16_k<<<dim3((nW4 + 255) / 256), 256, 0, stream>>>(Wih, Wbf, nW4);
  xg_gemm_k<<<dim3(G4H / 128, T_STEPS / 128), 256, 0, stream>>>(Abf, Wbf, bih, xg);
  lstm_scan_k<<<dim3(NWG), 512, 0, stream>>>(Whh, bhh, h1, c1, fcw, fcb, xg, hx, out);
}